// Round 3
// baseline (5377.961 us; speedup 1.0000x reference)
//
#include <hip/hip_runtime.h>
#include <hip/hip_bf16.h>

// Mlp_2_Layer_MMoE: B=131072, IN=113, E=4, D=8, H1=256, H2=113, T1=256, T2=128
// Low-workspace plan (peak 243 MB):
//   per-expert:  gemm1(emb->Y1e) ; gemm2(bn1+relu(Y1e) -> Y2 slice)
//   gates
//   per-domain:  gemm4(mix of bn2+relu(Y2) via gates -> Y3d) ;
//                gemm5(bn3+relu(Y3d) -> Y4d) ; final(select rows, bn4+relu, dot, sigmoid)
// BN(training): raw sum/sumsq via block-reduced atomics; finalize folded into the
// consumer kernel's prologue (scale/shift computed in LDS from raw stats).

#define B_ROWS 131072
#define NTILES (B_ROWS >> 7)
#define EPS_BN 1e-5f

typedef unsigned short bf_t;
typedef unsigned int u32;

__device__ __forceinline__ float bf2f(bf_t u) { return __uint_as_float(((u32)u) << 16); }
__device__ __forceinline__ bf_t f2bf(float f) {
    u32 x = __float_as_uint(f);
    u32 r = x + 0x7FFFu + ((x >> 16) & 1u);   // round-to-nearest-even
    return (bf_t)(r >> 16);
}

// ---------------------------------------------------------------------------
// gemm_core: Y[r][ycol0+c] = sum_k x(r,k) * W[k][c] + bias[c], r in [0,B)
//   XMODE 0: x = Xf[r*xrs + k]                          (fp32 global)
//   XMODE 1: x = relu(bn(Xb[r*xrs + k])), ch = k        (bf16 global, input BN)
//   XMODE 2: x = sum_e gates[r*32+e] * relu(bn(Xb[r*480 + e*120 + k])), ch = e*113+k
// Input BN scale/shift computed in prologue from raw stats (statS,statQ,gamma,beta).
// Output raw stats (sum, sumsq over batch) accumulated into oSum/oSq via atomics.
// Tile 128x128, K-chunk 32, 256 threads, 8x8 acc/thread.
// ---------------------------------------------------------------------------
template<int XMODE>
__global__ __launch_bounds__(256, 3)
void gemm_core(const float* __restrict__ Xf, const bf_t* __restrict__ Xb,
               int xrs, int K,
               const float* __restrict__ gates,
               const float* __restrict__ statS, const float* __restrict__ statQ,
               const float* __restrict__ gamma, const float* __restrict__ beta, int nchIn,
               const float* __restrict__ W, const float* __restrict__ bias, int N,
               bf_t* __restrict__ Y, int yrs, int ycol0,
               float* __restrict__ oSum, float* __restrict__ oSq)
{
    __shared__ float Xs[32][129];   // transposed: Xs[k][r], +1 pad
    __shared__ float Ws[32][128];
    __shared__ float scS[512], shS[512];

    const int tid = threadIdx.x;
    const int tx = tid & 15;        // 8 output columns each
    const int ty = tid >> 4;        // 8 output rows each
    const int c0 = blockIdx.y << 7;

    // ---- prologue: input-BN scale/shift from raw stats
    if (XMODE != 0) {
        for (int c = tid; c < nchIn; c += 256) {
            float m = statS[c] * (1.f / B_ROWS);
            float v = statQ[c] * (1.f / B_ROWS) - m * m;
            float s = gamma[c] * rsqrtf(v + EPS_BN);
            scS[c] = s;
            shS[c] = beta[c] - m * s;
        }
    }
    float bj[8];
#pragma unroll
    for (int j = 0; j < 8; ++j) {
        int c = c0 + tx * 8 + j;
        bj[j] = (c < N) ? bias[c] : 0.f;
    }
    __syncthreads();

    float csum[8], csq[8];
#pragma unroll
    for (int j = 0; j < 8; ++j) { csum[j] = 0.f; csq[j] = 0.f; }

    for (int rt = blockIdx.x; rt < NTILES; rt += gridDim.x) {
        const int r0 = rt << 7;
        float acc[8][8];
#pragma unroll
        for (int i = 0; i < 8; ++i)
#pragma unroll
            for (int j = 0; j < 8; ++j) acc[i][j] = 0.f;

        for (int kc = 0; kc < K; kc += 32) {
            // ---- stage W chunk (32 x 128), zero-padded
#pragma unroll
            for (int t = 0; t < 16; ++t) {
                int idx = tid + (t << 8);
                int kk = idx >> 7, cc = idx & 127;
                float v = 0.f;
                if (kc + kk < K && c0 + cc < N) v = W[(long)(kc + kk) * N + (c0 + cc)];
                Ws[kk][cc] = v;
            }
            // ---- stage X chunk transposed into Xs[k][r]
            if (XMODE == 0) {
#pragma unroll
                for (int t = 0; t < 16; ++t) {
                    int idx = tid + (t << 8);
                    int rr = idx >> 5, kk = idx & 31;
                    float v = 0.f;
                    if (kc + kk < K) v = Xf[(long)(r0 + rr) * xrs + (kc + kk)];
                    Xs[kk][rr] = v;
                }
            } else if (XMODE == 1) {
#pragma unroll
                for (int t = 0; t < 2; ++t) {
                    int idx = tid + (t << 8);
                    int rr = idx >> 2;              // 128 rows
                    int ks = (idx & 3) << 3;        // 0,8,16,24
                    float v[8];
                    if (kc + ks < K) {
                        uint4 raw = *(const uint4*)&Xb[(long)(r0 + rr) * xrs + (kc + ks)];
                        u32 w4[4] = {raw.x, raw.y, raw.z, raw.w};
#pragma unroll
                        for (int j = 0; j < 8; ++j) {
                            int k = kc + ks + j;
                            float f = 0.f;
                            if (k < K) {
                                f = bf2f((bf_t)((w4[j >> 1] >> ((j & 1) * 16)) & 0xffffu));
                                f = fmaxf(f * scS[k] + shS[k], 0.f);
                            }
                            v[j] = f;
                        }
                    } else {
#pragma unroll
                        for (int j = 0; j < 8; ++j) v[j] = 0.f;
                    }
#pragma unroll
                    for (int j = 0; j < 8; ++j) Xs[ks + j][rr] = v[j];
                }
            } else {    // XMODE 2: gated mixture over 4 experts
#pragma unroll
                for (int t = 0; t < 2; ++t) {
                    int idx = tid + (t << 8);
                    int rr = idx >> 2;
                    int ks = (idx & 3) << 3;
                    float v[8];
#pragma unroll
                    for (int j = 0; j < 8; ++j) v[j] = 0.f;
                    if (kc + ks < K) {
                        float4 g4 = *(const float4*)&gates[(long)(r0 + rr) * 32];
                        float ge[4] = {g4.x, g4.y, g4.z, g4.w};
#pragma unroll
                        for (int e = 0; e < 4; ++e) {
                            uint4 raw = *(const uint4*)&Xb[(long)(r0 + rr) * 480 + e * 120 + (kc + ks)];
                            u32 w4[4] = {raw.x, raw.y, raw.z, raw.w};
#pragma unroll
                            for (int j = 0; j < 8; ++j) {
                                int k = kc + ks + j;
                                if (k < K) {
                                    float f = bf2f((bf_t)((w4[j >> 1] >> ((j & 1) * 16)) & 0xffffu));
                                    int ch = e * 113 + k;
                                    f = fmaxf(f * scS[ch] + shS[ch], 0.f);
                                    v[j] = fmaf(ge[e], f, v[j]);
                                }
                            }
                        }
                    }
#pragma unroll
                    for (int j = 0; j < 8; ++j) Xs[ks + j][rr] = v[j];
                }
            }
            __syncthreads();

#pragma unroll 4
            for (int kk = 0; kk < 32; ++kk) {
                float xf[8], wf[8];
#pragma unroll
                for (int i = 0; i < 8; ++i) xf[i] = Xs[kk][ty * 8 + i];
#pragma unroll
                for (int j = 0; j < 8; ++j) wf[j] = Ws[kk][tx * 8 + j];
#pragma unroll
                for (int i = 0; i < 8; ++i)
#pragma unroll
                    for (int j = 0; j < 8; ++j) acc[i][j] = fmaf(xf[i], wf[j], acc[i][j]);
            }
            __syncthreads();
        }

        // ---- epilogue: bias, output-stat accumulation, bf16 store
#pragma unroll
        for (int i = 0; i < 8; ++i) {
            int r = r0 + ty * 8 + i;
            float y[8];
#pragma unroll
            for (int j = 0; j < 8; ++j) {
                y[j] = acc[i][j] + bj[j];   // out-of-range cols: acc=0, bj=0 -> 0
                csum[j] += y[j];
                csq[j]  += y[j] * y[j];
            }
            long yb = (long)r * yrs + ycol0 + c0 + tx * 8;
            if (c0 + tx * 8 + 8 <= N) {
                uint4 o;
                o.x = (u32)f2bf(y[0]) | ((u32)f2bf(y[1]) << 16);
                o.y = (u32)f2bf(y[2]) | ((u32)f2bf(y[3]) << 16);
                o.z = (u32)f2bf(y[4]) | ((u32)f2bf(y[5]) << 16);
                o.w = (u32)f2bf(y[6]) | ((u32)f2bf(y[7]) << 16);
                *(uint4*)(Y + yb) = o;
            } else {
#pragma unroll
                for (int j = 0; j < 8; ++j)
                    if (c0 + tx * 8 + j < N) Y[yb + j] = f2bf(y[j]);
            }
        }
    }

    // ---- block-reduce output stats, one atomic per column
    __syncthreads();
    float* red = &Ws[0][0];            // 16x128 floats scratch (Ws holds 32x128)
#pragma unroll
    for (int j = 0; j < 8; ++j) red[ty * 128 + tx * 8 + j] = csum[j];
    __syncthreads();
    if (tid < 128) {
        float s = 0.f;
#pragma unroll
        for (int t = 0; t < 16; ++t) s += red[t * 128 + tid];
        if (c0 + tid < N) atomicAdd(&oSum[c0 + tid], s);
    }
    __syncthreads();
#pragma unroll
    for (int j = 0; j < 8; ++j) red[ty * 128 + tx * 8 + j] = csq[j];
    __syncthreads();
    if (tid < 128) {
        float s = 0.f;
#pragma unroll
        for (int t = 0; t < 16; ++t) s += red[t * 128 + tid];
        if (c0 + tid < N) atomicAdd(&oSq[c0 + tid], s);
    }
}

// ---------------------------------------------------------------------------
// gates: gates[b][d*4+e] = softmax_e(emb[b] . Wg[d][:,e] + bg[d][e])
// 64 rows/block; 4 threads per row, each owns 2 domains.
// ---------------------------------------------------------------------------
__global__ __launch_bounds__(256)
void gates_kernel(const float* __restrict__ emb, const float* __restrict__ Wg,
                  const float* __restrict__ bg, float* __restrict__ gates)
{
    __shared__ float embS[64][116];
    __shared__ float WgS[8 * 113 * 4];
    __shared__ float bgS[32];
    const int tid = threadIdx.x;
    const int r0 = blockIdx.x << 6;

    for (int idx = tid; idx < 64 * 113; idx += 256) {
        int rr = idx / 113, kk = idx - rr * 113;
        embS[rr][kk] = emb[(long)(r0 + rr) * 113 + kk];
    }
    for (int idx = tid; idx < 8 * 113 * 4; idx += 256) WgS[idx] = Wg[idx];
    if (tid < 32) bgS[tid] = bg[tid];
    __syncthreads();

    const int q = tid & 3;
    const int r = tid >> 2;
#pragma unroll
    for (int p = 0; p < 2; ++p) {
        int d = q + p * 4;
        float lg[4] = {bgS[d * 4 + 0], bgS[d * 4 + 1], bgS[d * 4 + 2], bgS[d * 4 + 3]};
        for (int k = 0; k < 113; ++k) {
            float x = embS[r][k];
            const float* w = &WgS[(d * 113 + k) * 4];
#pragma unroll
            for (int e = 0; e < 4; ++e) lg[e] = fmaf(x, w[e], lg[e]);
        }
        float m = fmaxf(fmaxf(lg[0], lg[1]), fmaxf(lg[2], lg[3]));
        float ex[4], s = 0.f;
#pragma unroll
        for (int e = 0; e < 4; ++e) { ex[e] = expf(lg[e] - m); s += ex[e]; }
        float inv = 1.f / s;
        *(float4*)&gates[(long)(r0 + r) * 32 + d * 4] =
            make_float4(ex[0] * inv, ex[1] * inv, ex[2] * inv, ex[3] * inv);
    }
}

// ---------------------------------------------------------------------------
// final (per domain d): rows with dom[b]==d:
//   out[b] = sigmoid( relu(bn4(Y4d[b][:])) . w3 + b3 )
// bn4 finalize folded into prologue.
// ---------------------------------------------------------------------------
__global__ __launch_bounds__(256)
void final_kernel(const bf_t* __restrict__ Y4d, const int* __restrict__ dom,
                  const float* __restrict__ s4sum, const float* __restrict__ s4sq,
                  const float* __restrict__ g4, const float* __restrict__ b4,
                  const float* __restrict__ w3, const float* __restrict__ b3,
                  int d, float* __restrict__ out)
{
    __shared__ float sc[128], sh[128], wS[128];
    const int tid = threadIdx.x;
    if (tid < 128) {
        float m = s4sum[tid] * (1.f / B_ROWS);
        float v = s4sq[tid] * (1.f / B_ROWS) - m * m;
        float s = g4[tid] * rsqrtf(v + EPS_BN);
        sc[tid] = s;
        sh[tid] = b4[tid] - m * s;
        wS[tid] = w3[tid];
    }
    __syncthreads();
    const float bb = b3[0];
    for (long b = (long)blockIdx.x * 256 + tid; b < B_ROWS; b += (long)gridDim.x * 256) {
        if ((dom[b] & 7) == d) {    // &7: defensive vs bad domain values (no-op if 0..7)
            const bf_t* yp = Y4d + b * 128;
            float acc = bb;
            for (int c = 0; c < 128; c += 8) {
                uint4 raw = *(const uint4*)(yp + c);
                u32 w4[4] = {raw.x, raw.y, raw.z, raw.w};
#pragma unroll
                for (int j = 0; j < 8; ++j) {
                    float f = bf2f((bf_t)((w4[j >> 1] >> ((j & 1) * 16)) & 0xffffu));
                    float h = fmaxf(f * sc[c + j] + sh[c + j], 0.f);
                    acc = fmaf(h, wS[c + j], acc);
                }
            }
            out[b] = 1.f / (1.f + expf(-acc));
        }
    }
}

// ---------------------------------------------------------------------------
extern "C" void kernel_launch(void* const* d_in, const int* in_sizes, int n_in,
                              void* d_out, int out_size, void* d_ws, size_t ws_size,
                              hipStream_t stream)
{
    const float* emb = (const float*)d_in[0];
    const int*   dom = (const int*)d_in[1];
    const float* We1 = (const float*)d_in[2];
    const float* be1 = (const float*)d_in[3];
    const float* eg1 = (const float*)d_in[4];
    const float* eb1 = (const float*)d_in[5];
    const float* We2 = (const float*)d_in[6];
    const float* be2 = (const float*)d_in[7];
    const float* eg2 = (const float*)d_in[8];
    const float* eb2 = (const float*)d_in[9];
    const float* Wg  = (const float*)d_in[10];
    const float* bg  = (const float*)d_in[11];
    const float* Wt1 = (const float*)d_in[12];
    const float* bt1 = (const float*)d_in[13];
    const float* tg1 = (const float*)d_in[14];
    const float* tb1 = (const float*)d_in[15];
    const float* Wt2 = (const float*)d_in[16];
    const float* bt2 = (const float*)d_in[17];
    const float* tg2 = (const float*)d_in[18];
    const float* tb2 = (const float*)d_in[19];
    const float* Wt3 = (const float*)d_in[20];
    const float* bt3 = (const float*)d_in[21];
    float* out = (float*)d_out;

    char* ws = (char*)d_ws;
    // workspace layout (peak 243.3 MB):
    bf_t*  Y2    = (bf_t*)(ws);                    // [B][480] bf16, 125.8 MB
    float* gates = (float*)(ws + 125829120LL);     // [B][32] f32, 16.8 MB
    bf_t*  Yx    = (bf_t*)(ws + 142606336LL);      // Y1e / Y3d slot: [B][256] bf16, 67.1 MB
    bf_t*  Y4    = (bf_t*)(ws + 209715200LL);      // [B][128] bf16, 33.6 MB
    float* S     = (float*)(ws + 243269632LL);     // raw stats, 9096 floats

    float* S1s = S;           float* S1q = S1s + 1024;   // [4][256]
    float* S2s = S1q + 1024;  float* S2q = S2s + 452;    // [4][113]
    float* S3s = S2q + 452;   float* S3q = S3s + 2048;   // [8][256]
    float* S4s = S3q + 2048;  float* S4q = S4s + 1024;   // [8][128]

    hipMemsetAsync(S, 0, 9096 * sizeof(float), stream);

    // ---- expert phase (per expert e) ----
    for (int e = 0; e < 4; ++e) {
        // gemm1: emb [B,113] -> Y1e [B,256] + S1[e]
        gemm_core<0><<<dim3(512, 2), 256, 0, stream>>>(
            emb, nullptr, 113, 113,
            nullptr, nullptr, nullptr, nullptr, nullptr, 0,
            We1 + (long)e * 113 * 256, be1 + e * 256, 256,
            Yx, 256, 0, S1s + e * 256, S1q + e * 256);
        // gemm2: relu(bn1(Y1e)) [B,256] -> Y2[:, e*120 .. +113] + S2[e]
        gemm_core<1><<<dim3(512, 1), 256, 0, stream>>>(
            nullptr, Yx, 256, 256,
            nullptr, S1s + e * 256, S1q + e * 256, eg1 + e * 256, eb1 + e * 256, 256,
            We2 + (long)e * 256 * 113, be2 + e * 113, 113,
            Y2, 480, e * 120, S2s + e * 113, S2q + e * 113);
    }

    // ---- gates ----
    gates_kernel<<<2048, 256, 0, stream>>>(emb, Wg, bg, gates);

    // ---- tower phase (per domain d) ----
    for (int d = 0; d < 8; ++d) {
        // gemm4: x = sum_e gates * relu(bn2(Y2)) [B,113] -> Y3d [B,256] + S3[d]
        gemm_core<2><<<dim3(512, 2), 256, 0, stream>>>(
            nullptr, Y2, 480, 113,
            gates + d * 4, S2s, S2q, eg2, eb2, 452,
            Wt1 + (long)d * 113 * 256, bt1 + d * 256, 256,
            Yx, 256, 0, S3s + d * 256, S3q + d * 256);
        // gemm5: relu(bn3(Y3d)) [B,256] -> Y4d [B,128] + S4[d]
        gemm_core<1><<<dim3(512, 1), 256, 0, stream>>>(
            nullptr, Yx, 256, 256,
            nullptr, S3s + d * 256, S3q + d * 256, tg1 + d * 256, tb1 + d * 256, 256,
            Wt2 + (long)d * 256 * 128, bt2 + d * 128, 128,
            Y4, 128, 0, S4s + d * 128, S4q + d * 128);
        // final: select rows with dom==d, bn4+relu, dot Wt3, sigmoid
        final_kernel<<<1024, 256, 0, stream>>>(
            Y4, dom, S4s + d * 128, S4q + d * 128,
            tg2 + d * 128, tb2 + d * 128, Wt3 + d * 128, bt3 + d, d, out);
    }

    (void)in_sizes; (void)n_in; (void)out_size; (void)ws_size;
}

// Round 4
// 2239.776 us; speedup vs baseline: 2.4011x; 2.4011x over previous
//
#include <hip/hip_runtime.h>
#include <hip/hip_bf16.h>

// Mlp_2_Layer_MMoE: B=131072, IN=113, E=4, D=8, H1=256, H2=113, T1=256, T2=128
// Round 4: bf16 MFMA GEMMs (mfma_f32_16x16x32_bf16).
//   prep: weights -> bf16 transposed WT[c][k] (1.5MB); emb -> bf16 [B][128] (Y4 slot)
//   per-expert:  gemm1(embB->Y1e) ; gemm2(bn1+relu(Y1e) -> Y2 slice)
//   gates
//   per-domain:  gemm4(gated bn2+relu mix of Y2 -> Y3d) ; gemm5(bn3+relu -> Y4d) ; final
// BN(training): raw sum/sumsq via shfl-reduced atomics; finalize folded into consumer prologue.
// MFMA A/B loaded with a consistent k-bijection (k = 8*g + e) -> layout-safe.

#define B_ROWS 131072
#define NT64   (B_ROWS >> 6)     // 2048 row tiles of 64
#define EPS_BN 1e-5f

typedef unsigned short bf_t;
typedef unsigned int u32;
typedef short bf16x8 __attribute__((ext_vector_type(8)));
typedef float f32x4  __attribute__((ext_vector_type(4)));

__device__ __forceinline__ float bf2f(bf_t u) { return __uint_as_float(((u32)u) << 16); }
__device__ __forceinline__ bf_t f2bf(float f) {
    u32 x = __float_as_uint(f);
    u32 r = x + 0x7FFFu + ((x >> 16) & 1u);   // round-to-nearest-even
    return (bf_t)(r >> 16);
}

// ---------------------------------------------------------------------------
// prep_w: WT[g][c][kk] = (kk<K && c<N) ? bf16(W[g][kk*N + c]) : 0
// ---------------------------------------------------------------------------
__global__ __launch_bounds__(256)
void prep_w(const float* __restrict__ W, bf_t* __restrict__ WT,
            int G, int K, int N, int CPAD, int KP)
{
    long total = (long)G * CPAD * KP;
    for (long idx = (long)blockIdx.x * 256 + threadIdx.x; idx < total;
         idx += (long)gridDim.x * 256) {
        int kk = (int)(idx % KP);
        long t = idx / KP;
        int c = (int)(t % CPAD);
        int g = (int)(t / CPAD);
        float v = 0.f;
        if (kk < K && c < N) v = W[((long)g * K + kk) * N + c];
        WT[idx] = f2bf(v);
    }
}

// ---------------------------------------------------------------------------
// prep_emb: embB[b][c] = c<113 ? bf16(emb[b*113+c]) : 0   (stride 128)
// ---------------------------------------------------------------------------
__global__ __launch_bounds__(256)
void prep_emb(const float* __restrict__ emb, bf_t* __restrict__ embB)
{
    long idx = (long)blockIdx.x * 256 + threadIdx.x;   // exact grid: B*128/256 blocks
    int c = (int)(idx & 127);
    long b = idx >> 7;
    float v = (c < 113) ? emb[b * 113 + c] : 0.f;
    embB[idx] = f2bf(v);
}

// ---------------------------------------------------------------------------
// gemm_mfma: Y[r][ycol0+c] = sum_k x(r,k) * WT[c][k] + bias[c]
//   XMODE 0: x = X[r*xrs + k]                       (bf16, no transform; pads are zero)
//   XMODE 1: x = relu(bn(X[r*xrs + k])), ch = k
//   XMODE 2: x = sum_e gates[r*32+e] * relu(bn(X[r*480 + e*120 + k])), ch = e*113+k,
//            masked to k < Kreal (pad cols of Y2 are poison)
// Tile: 64 rows x NTILE cols, 256 threads = 4 waves (wave w owns cols [w*NTILE/4, +NTILE/4)).
// K-chunk 32; per chunk each wave: 4 A-frags + CF B-frags (ds_read_b128) + 4*CF mfma.
// Output raw stats (sum,sumsq) -> shfl-reduce over lane groups -> 1 atomic/col/block.
// ---------------------------------------------------------------------------
template<int XMODE, int NTILE>
__global__ __launch_bounds__(256, 2)
void gemm_mfma(const bf_t* __restrict__ X, int xrs, int Kreal, int KT,
               const float* __restrict__ gates,
               const float* __restrict__ statS, const float* __restrict__ statQ,
               const float* __restrict__ gamma, const float* __restrict__ beta, int nchIn,
               const bf_t* __restrict__ WT, int wks,
               const float* __restrict__ bias, int N,
               bf_t* __restrict__ Y, int yrs, int ycol0,
               float* __restrict__ oSum, float* __restrict__ oSq)
{
    constexpr int WC = NTILE / 4;      // cols per wave
    constexpr int CF = WC / 16;        // 16x16 col-frags per wave (2 or 4)

    __shared__ bf_t Xs[64 * 40];       // [row][k], stride 40 (80B, 16B-aligned)
    __shared__ bf_t Ws[NTILE * 40];    // [col][k], stride 40
    __shared__ float scS[512], shS[512];

    const int tid  = threadIdx.x;
    const int w    = tid >> 6;
    const int lane = tid & 63;
    const int g    = lane >> 4;
    const int lr   = lane & 15;

    // ---- prologue: input-BN scale/shift from raw stats
    if (XMODE != 0) {
        for (int c = tid; c < nchIn; c += 256) {
            float m = statS[c] * (1.f / B_ROWS);
            float v = statQ[c] * (1.f / B_ROWS) - m * m;
            float s = gamma[c] * rsqrtf(v + EPS_BN);
            scS[c] = s;
            shS[c] = beta[c] - m * s;
        }
    }
    float bj[CF];
#pragma unroll
    for (int ci = 0; ci < CF; ++ci) {
        int col = w * WC + ci * 16 + lr;
        bj[ci] = (col < N) ? bias[col] : 0.f;
    }
    __syncthreads();

    float csum[CF], csq[CF];
#pragma unroll
    for (int ci = 0; ci < CF; ++ci) { csum[ci] = 0.f; csq[ci] = 0.f; }

    const int sr = tid >> 2;           // staging row/col 0..63
    const int so = (tid & 3) << 3;     // staging k-offset 0,8,16,24

    for (int rt = blockIdx.x; rt < NT64; rt += gridDim.x) {
        const int r0 = rt << 6;
        f32x4 acc[4][CF];
#pragma unroll
        for (int ri = 0; ri < 4; ++ri)
#pragma unroll
            for (int ci = 0; ci < CF; ++ci) acc[ri][ci] = (f32x4){0.f, 0.f, 0.f, 0.f};

        for (int kt = 0; kt < KT; ++kt) {
            const int kc = kt << 5;
            // ---- stage X chunk: 64 rows x 32 k, one b128 per thread
            if (XMODE == 0) {
                *(uint4*)&Xs[sr * 40 + so] =
                    *(const uint4*)&X[(long)(r0 + sr) * xrs + kc + so];
            } else if (XMODE == 1) {
                uint4 raw = *(const uint4*)&X[(long)(r0 + sr) * xrs + kc + so];
                u32 w4[4] = {raw.x, raw.y, raw.z, raw.w};
                u32 o4[4];
#pragma unroll
                for (int p = 0; p < 4; ++p) {
                    int k0 = kc + so + p * 2;
                    float f0 = bf2f((bf_t)(w4[p] & 0xffffu));
                    float f1 = bf2f((bf_t)(w4[p] >> 16));
                    f0 = fmaxf(f0 * scS[k0] + shS[k0], 0.f);
                    f1 = fmaxf(f1 * scS[k0 + 1] + shS[k0 + 1], 0.f);
                    o4[p] = (u32)f2bf(f0) | ((u32)f2bf(f1) << 16);
                }
                *(uint4*)&Xs[sr * 40 + so] = make_uint4(o4[0], o4[1], o4[2], o4[3]);
            } else {   // XMODE 2: gated 4-expert mixture
                float vv[8];
#pragma unroll
                for (int j = 0; j < 8; ++j) vv[j] = 0.f;
                float4 g4 = *(const float4*)&gates[(long)(r0 + sr) * 32];
                float ge[4] = {g4.x, g4.y, g4.z, g4.w};
#pragma unroll
                for (int e = 0; e < 4; ++e) {
                    uint4 raw = *(const uint4*)&X[(long)(r0 + sr) * 480 + e * 120 + kc + so];
                    u32 w4[4] = {raw.x, raw.y, raw.z, raw.w};
#pragma unroll
                    for (int j = 0; j < 8; ++j) {
                        int k = kc + so + j;
                        if (k < Kreal) {
                            float f = bf2f((bf_t)((w4[j >> 1] >> ((j & 1) * 16)) & 0xffffu));
                            int ch = e * 113 + k;
                            f = fmaxf(f * scS[ch] + shS[ch], 0.f);
                            vv[j] = fmaf(ge[e], f, vv[j]);
                        }
                    }
                }
                u32 o4[4];
#pragma unroll
                for (int p = 0; p < 4; ++p)
                    o4[p] = (u32)f2bf(vv[p * 2]) | ((u32)f2bf(vv[p * 2 + 1]) << 16);
                *(uint4*)&Xs[sr * 40 + so] = make_uint4(o4[0], o4[1], o4[2], o4[3]);
            }
            // ---- stage W chunk: NTILE cols x 32 k (copy-through from bf16 WT)
#pragma unroll
            for (int t = 0; t < NTILE / 64; ++t) {
                int c = t * 64 + sr;
                *(uint4*)&Ws[c * 40 + so] = *(const uint4*)&WT[(long)c * wks + kc + so];
            }
            __syncthreads();

            // ---- fragments + MFMA (k-bijection: elem e <-> k = kc + g*8 + e, both operands)
            bf16x8 af[4];
#pragma unroll
            for (int ri = 0; ri < 4; ++ri)
                af[ri] = *(const bf16x8*)&Xs[(ri * 16 + lr) * 40 + g * 8];
#pragma unroll
            for (int ci = 0; ci < CF; ++ci) {
                bf16x8 bfr = *(const bf16x8*)&Ws[(w * WC + ci * 16 + lr) * 40 + g * 8];
#pragma unroll
                for (int ri = 0; ri < 4; ++ri)
                    acc[ri][ci] = __builtin_amdgcn_mfma_f32_16x16x32_bf16(
                        af[ri], bfr, acc[ri][ci], 0, 0, 0);
            }
            __syncthreads();
        }

        // ---- epilogue: bias, stats, bf16 store (C/D: col=lane&15, row=g*4+reg)
#pragma unroll
        for (int ci = 0; ci < CF; ++ci) {
            int col = w * WC + ci * 16 + lr;
            bool cv = col < N;
#pragma unroll
            for (int ri = 0; ri < 4; ++ri) {
                f32x4 a = acc[ri][ci];
#pragma unroll
                for (int reg = 0; reg < 4; ++reg) {
                    float y = a[reg] + bj[ci];
                    csum[ci] += y;
                    csq[ci]  += y * y;
                    if (cv)
                        Y[(long)(r0 + ri * 16 + g * 4 + reg) * yrs + ycol0 + col] = f2bf(y);
                }
            }
        }
    }

    // ---- stats: reduce over the 4 lane-groups, one atomic per column per block
#pragma unroll
    for (int ci = 0; ci < CF; ++ci) {
        float s = csum[ci], q = csq[ci];
        s += __shfl_xor(s, 16); s += __shfl_xor(s, 32);
        q += __shfl_xor(q, 16); q += __shfl_xor(q, 32);
        if (lane < 16) {
            int col = w * WC + ci * 16 + lane;
            if (col < N) {
                atomicAdd(&oSum[col], s);
                atomicAdd(&oSq[col], q);
            }
        }
    }
}

// ---------------------------------------------------------------------------
// gates: gates[b][d*4+e] = softmax_e(emb[b] . Wg[d][:,e] + bg[d][e])
// ---------------------------------------------------------------------------
__global__ __launch_bounds__(256)
void gates_kernel(const float* __restrict__ emb, const float* __restrict__ Wg,
                  const float* __restrict__ bg, float* __restrict__ gates)
{
    __shared__ float embS[64][116];
    __shared__ float WgS[8 * 113 * 4];
    __shared__ float bgS[32];
    const int tid = threadIdx.x;
    const int r0 = blockIdx.x << 6;

    for (int idx = tid; idx < 64 * 113; idx += 256) {
        int rr = idx / 113, kk = idx - rr * 113;
        embS[rr][kk] = emb[(long)(r0 + rr) * 113 + kk];
    }
    for (int idx = tid; idx < 8 * 113 * 4; idx += 256) WgS[idx] = Wg[idx];
    if (tid < 32) bgS[tid] = bg[tid];
    __syncthreads();

    const int q = tid & 3;
    const int r = tid >> 2;
#pragma unroll
    for (int p = 0; p < 2; ++p) {
        int d = q + p * 4;
        float lg[4] = {bgS[d * 4 + 0], bgS[d * 4 + 1], bgS[d * 4 + 2], bgS[d * 4 + 3]};
        for (int k = 0; k < 113; ++k) {
            float x = embS[r][k];
            const float* wp = &WgS[(d * 113 + k) * 4];
#pragma unroll
            for (int e = 0; e < 4; ++e) lg[e] = fmaf(x, wp[e], lg[e]);
        }
        float m = fmaxf(fmaxf(lg[0], lg[1]), fmaxf(lg[2], lg[3]));
        float ex[4], s = 0.f;
#pragma unroll
        for (int e = 0; e < 4; ++e) { ex[e] = expf(lg[e] - m); s += ex[e]; }
        float inv = 1.f / s;
        *(float4*)&gates[(long)(r0 + r) * 32 + d * 4] =
            make_float4(ex[0] * inv, ex[1] * inv, ex[2] * inv, ex[3] * inv);
    }
}

// ---------------------------------------------------------------------------
// final (per domain d): rows with dom[b]==d:
//   out[b] = sigmoid( relu(bn4(Y4d[b][:])) . w3 + b3 )
// ---------------------------------------------------------------------------
__global__ __launch_bounds__(256)
void final_kernel(const bf_t* __restrict__ Y4d, const int* __restrict__ dom,
                  const float* __restrict__ s4sum, const float* __restrict__ s4sq,
                  const float* __restrict__ g4, const float* __restrict__ b4,
                  const float* __restrict__ w3, const float* __restrict__ b3,
                  int d, float* __restrict__ out)
{
    __shared__ float sc[128], sh[128], wS[128];
    const int tid = threadIdx.x;
    if (tid < 128) {
        float m = s4sum[tid] * (1.f / B_ROWS);
        float v = s4sq[tid] * (1.f / B_ROWS) - m * m;
        float s = g4[tid] * rsqrtf(v + EPS_BN);
        sc[tid] = s;
        sh[tid] = b4[tid] - m * s;
        wS[tid] = w3[tid];
    }
    __syncthreads();
    const float bb = b3[0];
    for (long b = (long)blockIdx.x * 256 + tid; b < B_ROWS; b += (long)gridDim.x * 256) {
        if ((dom[b] & 7) == d) {
            const bf_t* yp = Y4d + b * 128;
            float acc = bb;
            for (int c = 0; c < 128; c += 8) {
                uint4 raw = *(const uint4*)(yp + c);
                u32 w4[4] = {raw.x, raw.y, raw.z, raw.w};
#pragma unroll
                for (int j = 0; j < 8; ++j) {
                    float f = bf2f((bf_t)((w4[j >> 1] >> ((j & 1) * 16)) & 0xffffu));
                    float h = fmaxf(f * sc[c + j] + sh[c + j], 0.f);
                    acc = fmaf(h, wS[c + j], acc);
                }
            }
            out[b] = 1.f / (1.f + expf(-acc));
        }
    }
}

// ---------------------------------------------------------------------------
extern "C" void kernel_launch(void* const* d_in, const int* in_sizes, int n_in,
                              void* d_out, int out_size, void* d_ws, size_t ws_size,
                              hipStream_t stream)
{
    const float* emb = (const float*)d_in[0];
    const int*   dom = (const int*)d_in[1];
    const float* We1 = (const float*)d_in[2];
    const float* be1 = (const float*)d_in[3];
    const float* eg1 = (const float*)d_in[4];
    const float* eb1 = (const float*)d_in[5];
    const float* We2 = (const float*)d_in[6];
    const float* be2 = (const float*)d_in[7];
    const float* eg2 = (const float*)d_in[8];
    const float* eb2 = (const float*)d_in[9];
    const float* Wg  = (const float*)d_in[10];
    const float* bg  = (const float*)d_in[11];
    const float* Wt1 = (const float*)d_in[12];
    const float* bt1 = (const float*)d_in[13];
    const float* tg1 = (const float*)d_in[14];
    const float* tb1 = (const float*)d_in[15];
    const float* Wt2 = (const float*)d_in[16];
    const float* bt2 = (const float*)d_in[17];
    const float* tg2 = (const float*)d_in[18];
    const float* tb2 = (const float*)d_in[19];
    const float* Wt3 = (const float*)d_in[20];
    const float* bt3 = (const float*)d_in[21];
    float* out = (float*)d_out;

    char* ws = (char*)d_ws;
    // workspace layout (peak ~244.9 MB):
    bf_t*  Y2    = (bf_t*)(ws);                    // [B][480] bf16, 125.8 MB
    float* gates = (float*)(ws + 125829120LL);     // [B][32] f32, 16.8 MB
    bf_t*  Yx    = (bf_t*)(ws + 142606336LL);      // Y1e / Y3d slot: [B][256] bf16, 67.1 MB
    bf_t*  Y4    = (bf_t*)(ws + 209715200LL);      // [B][128] bf16, 33.55 MB (embB first)
    float* S     = (float*)(ws + 243269632LL);     // raw stats, 9096 f32
    bf_t*  WTa   = (bf_t*)(ws + 243306496LL);      // transposed bf16 weights, 1.5 MB

    bf_t* embB = Y4;                 // [B][128] bf16 — dead before gemm5 writes Y4
    bf_t* We1T = WTa;                // [4][256][128]
    bf_t* We2T = We1T + 131072;      // [4][128][256]
    bf_t* Wt1T = We2T + 131072;      // [8][256][128]
    bf_t* Wt2T = Wt1T + 262144;      // [8][128][256]

    float* S1s = S;           float* S1q = S1s + 1024;   // [4][256]
    float* S2s = S1q + 1024;  float* S2q = S2s + 452;    // [4][113]
    float* S3s = S2q + 452;   float* S3q = S3s + 2048;   // [8][256]
    float* S4s = S3q + 2048;  float* S4q = S4s + 1024;   // [8][128]

    hipMemsetAsync(S, 0, 9096 * sizeof(float), stream);

    // ---- prep: weight transpose/convert + emb convert ----
    prep_w<<<512, 256, 0, stream>>>(We1, We1T, 4, 113, 256, 256, 128);
    prep_w<<<512, 256, 0, stream>>>(We2, We2T, 4, 256, 113, 128, 256);
    prep_w<<<1024, 256, 0, stream>>>(Wt1, Wt1T, 8, 113, 256, 256, 128);
    prep_w<<<1024, 256, 0, stream>>>(Wt2, Wt2T, 8, 256, 128, 128, 256);
    prep_emb<<<65536, 256, 0, stream>>>(emb, embB);

    // ---- gates (independent of experts) ----
    gates_kernel<<<2048, 256, 0, stream>>>(emb, Wg, bg, gates);

    // ---- expert phase (per expert e) ----
    for (int e = 0; e < 4; ++e) {
        // gemm1: embB [B,128](113) -> Y1e [B,256] + S1[e]
        gemm_mfma<0, 256><<<1024, 256, 0, stream>>>(
            embB, 128, 128, 4,
            nullptr, nullptr, nullptr, nullptr, nullptr, 0,
            We1T + (long)e * 256 * 128, 128,
            be1 + e * 256, 256,
            Yx, 256, 0, S1s + e * 256, S1q + e * 256);
        // gemm2: relu(bn1(Y1e)) [B,256] -> Y2[:, e*120 .. +113] + S2[e]
        gemm_mfma<1, 128><<<1024, 256, 0, stream>>>(
            Yx, 256, 256, 8,
            nullptr, S1s + e * 256, S1q + e * 256, eg1 + e * 256, eb1 + e * 256, 256,
            We2T + (long)e * 128 * 256, 256,
            be2 + e * 113, 113,
            Y2, 480, e * 120, S2s + e * 113, S2q + e * 113);
    }

    // ---- tower phase (per domain d) ----
    for (int d = 0; d < 8; ++d) {
        // gemm4: x = sum_e gates * relu(bn2(Y2)) [B,113] -> Y3d [B,256] + S3[d]
        gemm_mfma<2, 256><<<1024, 256, 0, stream>>>(
            Y2, 480, 113, 4,
            gates + d * 4, S2s, S2q, eg2, eb2, 452,
            Wt1T + (long)d * 256 * 128, 128,
            bt1 + d * 256, 256,
            Yx, 256, 0, S3s + d * 256, S3q + d * 256);
        // gemm5: relu(bn3(Y3d)) [B,256] -> Y4d [B,128] + S4[d]
        gemm_mfma<1, 128><<<1024, 256, 0, stream>>>(
            Yx, 256, 256, 8,
            nullptr, S3s + d * 256, S3q + d * 256, tg1 + d * 256, tb1 + d * 256, 256,
            Wt2T + (long)d * 128 * 256, 256,
            bt2 + d * 128, 128,
            Y4, 128, 0, S4s + d * 128, S4q + d * 128);
        // final: select rows with dom==d, bn4+relu, dot Wt3, sigmoid
        final_kernel<<<1024, 256, 0, stream>>>(
            Y4, dom, S4s + d * 128, S4q + d * 128,
            tg2 + d * 128, tb2 + d * 128, Wt3 + d * 128, bt3 + d, d, out);
    }

    (void)in_sizes; (void)n_in; (void)out_size; (void)ws_size;
}

// Round 5
// 1787.755 us; speedup vs baseline: 3.0082x; 1.2528x over previous
//
#include <hip/hip_runtime.h>
#include <hip/hip_bf16.h>

// Mlp_2_Layer_MMoE round 5: W-resident-LDS, 8-wave 128-row tiles, 1 barrier/chunk,
// cross-iteration prefetch, selected-row Y4 stores.
// Pipeline unchanged: per-expert gemm1,gemm2 ; gates ; per-domain gemm4,gemm5,final.
// BN(training): raw sum/sumsq via shfl-reduced atomics; finalize in consumer prologue.

#define B_ROWS 131072
#define EPS_BN 1e-5f

typedef unsigned short bf_t;
typedef unsigned int u32;
typedef short bf16x8 __attribute__((ext_vector_type(8)));
typedef float f32x4  __attribute__((ext_vector_type(4)));

__device__ __forceinline__ float bf2f(bf_t u) { return __uint_as_float(((u32)u) << 16); }
__device__ __forceinline__ bf_t f2bf(float f) {
    u32 x = __float_as_uint(f);
    u32 r = x + 0x7FFFu + ((x >> 16) & 1u);   // round-to-nearest-even
    return (bf_t)(r >> 16);
}

// ---------------------------------------------------------------------------
// prep_w: WT[g][c][kk] = (kk<K && c<N) ? bf16(W[g][kk*N + c]) : 0
// ---------------------------------------------------------------------------
__global__ __launch_bounds__(256)
void prep_w(const float* __restrict__ W, bf_t* __restrict__ WT,
            int G, int K, int N, int CPAD, int KP)
{
    long total = (long)G * CPAD * KP;
    for (long idx = (long)blockIdx.x * 256 + threadIdx.x; idx < total;
         idx += (long)gridDim.x * 256) {
        int kk = (int)(idx % KP);
        long t = idx / KP;
        int c = (int)(t % CPAD);
        int g = (int)(t / CPAD);
        float v = 0.f;
        if (kk < K && c < N) v = W[((long)g * K + kk) * N + c];
        WT[idx] = f2bf(v);
    }
}

// ---------------------------------------------------------------------------
// prep_emb: embB[b][c0..c0+7] = bf16(emb[b][c0..]), zero-padded to 128, uint4 stores
// ---------------------------------------------------------------------------
__global__ __launch_bounds__(256)
void prep_emb(const float* __restrict__ emb, bf_t* __restrict__ embB)
{
    const long total = (long)B_ROWS * 16;          // 8-col units
    for (long idx = (long)blockIdx.x * 256 + threadIdx.x; idx < total;
         idx += (long)gridDim.x * 256) {
        long b = idx >> 4;
        int c0 = (int)(idx & 15) << 3;
        u32 o[4];
#pragma unroll
        for (int p = 0; p < 4; ++p) {
            int c = c0 + p * 2;
            float f0 = (c < 113)     ? emb[b * 113 + c]     : 0.f;
            float f1 = (c + 1 < 113) ? emb[b * 113 + c + 1] : 0.f;
            o[p] = (u32)f2bf(f0) | ((u32)f2bf(f1) << 16);
        }
        *(uint4*)&embB[b * 128 + c0] = make_uint4(o[0], o[1], o[2], o[3]);
    }
}

// ---------------------------------------------------------------------------
// gemm_big: Y[r][ycol0+c] = sum_k x(r,k) * WT[c][k] + bias[c]
//   XMODE 0: x = X[r*xrs + k]                  (bf16, pads zero)
//   XMODE 1: x = relu(bn(X[r*xrs + k])), ch=k
//   XMODE 2: x = sum_e gates[r*32+e]*relu(bn(X[r*480+e*120+k])), ch=e*113+k, k<Kreal
// Block: 512 thr = 8 waves (2 row-halves x 4 col-quarters), tile 128 rows x NTILE.
// W resident in LDS ([col][KPAD+8]); X double-buffered ([row][136]); K-chunk 128.
// One barrier per chunk; XMODE0/1 prefetch next chunk's loads across the MFMA.
// SEL: store Y rows only where dom[row]==dsel (stats still over all rows).
// ---------------------------------------------------------------------------
template<int XMODE, int NTILE, int KPAD, bool SEL>
__global__ __launch_bounds__(512, 1)
void gemm_big(const bf_t* __restrict__ X, int xrs, int Kreal,
              const float* __restrict__ gates,
              const float* __restrict__ statS, const float* __restrict__ statQ,
              const float* __restrict__ gamma, const float* __restrict__ beta, int nchIn,
              const bf_t* __restrict__ WT,
              const float* __restrict__ bias, int N,
              bf_t* __restrict__ Y, int yrs, int ycol0,
              const int* __restrict__ dom, int dsel,
              float* __restrict__ oSum, float* __restrict__ oSq)
{
    constexpr int NCH  = KPAD / 128;       // chunks per tile (1 or 2)
    constexpr int WSTR = KPAD + 8;         // W LDS stride (bank-spread)
    constexpr int XSTR = 136;              // X LDS stride
    constexpr int WCW  = NTILE / 4;        // cols per wave
    constexpr int CF   = WCW / 16;         // col frags per wave
    constexpr int TPB  = 4;                // tiles per block
    constexpr int NIT  = TPB * NCH;

    __shared__ bf_t  WsL[NTILE * WSTR];
    __shared__ bf_t  XsL[2][128 * XSTR];
    __shared__ float scS[512], shS[512];

    const int tid  = threadIdx.x;
    const int lane = tid & 63;
    const int w    = tid >> 6;
    const int wr   = w >> 2, wc = w & 3;
    const int g    = lane >> 4, lr = lane & 15;
    const int sr   = tid >> 2;             // staging row 0..127
    const int so   = (tid & 3) << 5;       // staging k-offset 0,32,64,96
    const long tb0 = (long)blockIdx.x * TPB;

    // ---- W tile -> LDS (once) ----
#pragma unroll
    for (int i = 0; i < NTILE * KPAD / 8 / 512; ++i) {
        int idx = tid + i * 512;
        int col = idx / (KPAD / 8);
        int ks  = (idx % (KPAD / 8)) * 8;
        *(uint4*)&WsL[col * WSTR + ks] = *(const uint4*)&WT[(long)col * KPAD + ks];
    }
    // ---- input-BN scale/shift ----
    if (XMODE != 0) {
        for (int c = tid; c < nchIn; c += 512) {
            float m = statS[c] * (1.f / B_ROWS);
            float v = statQ[c] * (1.f / B_ROWS) - m * m;
            float s = gamma[c] * rsqrtf(v + EPS_BN);
            scS[c] = s;
            shS[c] = beta[c] - m * s;
        }
    }
    float bj[CF];
#pragma unroll
    for (int ci = 0; ci < CF; ++ci) {
        int col = wc * WCW + ci * 16 + lr;
        bj[ci] = (col < N) ? bias[col] : 0.f;
    }
    __syncthreads();   // W + scS ready

    f32x4 acc[4][CF];
#pragma unroll
    for (int ri = 0; ri < 4; ++ri)
#pragma unroll
        for (int ci = 0; ci < CF; ++ci) acc[ri][ci] = (f32x4){0.f, 0.f, 0.f, 0.f};
    float csum[CF], csq[CF];
#pragma unroll
    for (int ci = 0; ci < CF; ++ci) { csum[ci] = 0.f; csq[ci] = 0.f; }

    // ---- helpers ----
    auto issue4 = [&](int it, uint4* r) {            // XMODE 0/1 global loads
        int t = it / NCH, ck = (it % NCH) << 7;
        long row = (tb0 + t) * 128 + sr;
#pragma unroll
        for (int j = 0; j < 4; ++j)
            r[j] = *(const uint4*)&X[row * (long)xrs + ck + so + j * 8];
    };
    auto twrite = [&](int it, const uint4* r) {      // transform + LDS write
        bf_t* dst = &XsL[it & 1][sr * XSTR + so];
        if (XMODE == 0) {
#pragma unroll
            for (int j = 0; j < 4; ++j) *(uint4*)(dst + j * 8) = r[j];
        } else {
            int ck = (it % NCH) << 7;
#pragma unroll
            for (int j = 0; j < 4; ++j) {
                u32 q[4] = {r[j].x, r[j].y, r[j].z, r[j].w};
                u32 o[4];
#pragma unroll
                for (int p = 0; p < 4; ++p) {
                    int k0 = ck + so + j * 8 + p * 2;
                    float f0 = fmaxf(bf2f((bf_t)(q[p] & 0xffffu)) * scS[k0] + shS[k0], 0.f);
                    float f1 = fmaxf(bf2f((bf_t)(q[p] >> 16)) * scS[k0 + 1] + shS[k0 + 1], 0.f);
                    o[p] = (u32)f2bf(f0) | ((u32)f2bf(f1) << 16);
                }
                *(uint4*)(dst + j * 8) = make_uint4(o[0], o[1], o[2], o[3]);
            }
        }
    };
    auto stage2 = [&](int it) {                      // XMODE 2: gated mix, JIT
        long row = (tb0 + it) * 128 + sr;            // NCH==1 for XMODE2
        float4 g4 = *(const float4*)&gates[row * 32];
        uint4 r[16];
#pragma unroll
        for (int j = 0; j < 4; ++j)
#pragma unroll
            for (int e = 0; e < 4; ++e)
                r[j * 4 + e] = *(const uint4*)&X[row * 480 + e * 120 + so + j * 8];
        float ge[4] = {g4.x, g4.y, g4.z, g4.w};
        bf_t* dst = &XsL[it & 1][sr * XSTR + so];
#pragma unroll
        for (int j = 0; j < 4; ++j) {
            float vv[8];
#pragma unroll
            for (int p = 0; p < 8; ++p) vv[p] = 0.f;
#pragma unroll
            for (int e = 0; e < 4; ++e) {
                u32 q[4] = {r[j * 4 + e].x, r[j * 4 + e].y, r[j * 4 + e].z, r[j * 4 + e].w};
#pragma unroll
                for (int p = 0; p < 8; ++p) {
                    int k = so + j * 8 + p;
                    if (k < Kreal) {
                        float f = bf2f((bf_t)((q[p >> 1] >> ((p & 1) * 16)) & 0xffffu));
                        int ch = e * 113 + k;
                        f = fmaxf(f * scS[ch] + shS[ch], 0.f);
                        vv[p] = fmaf(ge[e], f, vv[p]);
                    }
                }
            }
            u32 o[4];
#pragma unroll
            for (int p = 0; p < 4; ++p)
                o[p] = (u32)f2bf(vv[p * 2]) | ((u32)f2bf(vv[p * 2 + 1]) << 16);
            *(uint4*)(dst + j * 8) = make_uint4(o[0], o[1], o[2], o[3]);
        }
    };
    auto do_mfma = [&](int it) {
        const bf_t* xb = XsL[it & 1];
        const int ck = (it % NCH) << 7;
#pragma unroll
        for (int kt = 0; kt < 4; ++kt) {
            bf16x8 af[4];
#pragma unroll
            for (int ri = 0; ri < 4; ++ri)
                af[ri] = *(const bf16x8*)&xb[(wr * 64 + ri * 16 + lr) * XSTR + kt * 32 + g * 8];
#pragma unroll
            for (int ci = 0; ci < CF; ++ci) {
                bf16x8 bf8 = *(const bf16x8*)&WsL[(wc * WCW + ci * 16 + lr) * WSTR + ck + kt * 32 + g * 8];
#pragma unroll
                for (int ri = 0; ri < 4; ++ri)
                    acc[ri][ci] = __builtin_amdgcn_mfma_f32_16x16x32_bf16(
                        af[ri], bf8, acc[ri][ci], 0, 0, 0);
            }
        }
    };
    auto epi = [&](int t) {
        const long row0 = (tb0 + t) * 128;
#pragma unroll
        for (int ci = 0; ci < CF; ++ci) {
            int col = wc * WCW + ci * 16 + lr;
            bool cv = col < N;
#pragma unroll
            for (int ri = 0; ri < 4; ++ri) {
#pragma unroll
                for (int reg = 0; reg < 4; ++reg) {
                    long row = row0 + wr * 64 + ri * 16 + g * 4 + reg;
                    float y = acc[ri][ci][reg] + bj[ci];
                    csum[ci] += y;
                    csq[ci]  += y * y;
                    bool st = cv;
                    if (SEL) st = st && (dom[row] == dsel);
                    if (st) Y[row * (long)yrs + ycol0 + col] = f2bf(y);
                    acc[ri][ci][reg] = 0.f;
                }
            }
        }
    };

    // ---- main loop: one barrier per chunk, dbuf rotation ----
    if (XMODE != 2) {
        uint4 rA[4], rB[4];
        issue4(0, rA);
#pragma unroll 1
        for (int ip = 0; ip < NIT; ip += 2) {
            if (ip + 1 < NIT) issue4(ip + 1, rB);
            twrite(ip, rA);
            __syncthreads();
            do_mfma(ip);
            if ((ip % NCH) == NCH - 1) epi(ip / NCH);
            if (ip + 2 < NIT) issue4(ip + 2, rA);
            twrite(ip + 1, rB);
            __syncthreads();
            do_mfma(ip + 1);
            if (((ip + 1) % NCH) == NCH - 1) epi((ip + 1) / NCH);
        }
    } else {
#pragma unroll 1
        for (int it = 0; it < NIT; ++it) {
            stage2(it);
            __syncthreads();
            do_mfma(it);
            epi(it);
        }
    }

    // ---- stats flush: shfl over lane groups, one atomic per col per half ----
#pragma unroll
    for (int ci = 0; ci < CF; ++ci) {
        float s = csum[ci], q = csq[ci];
        s += __shfl_xor(s, 16); s += __shfl_xor(s, 32);
        q += __shfl_xor(q, 16); q += __shfl_xor(q, 32);
        if (lane < 16) {
            int col = wc * WCW + ci * 16 + lane;
            if (col < N) {
                atomicAdd(&oSum[col], s);
                atomicAdd(&oSq[col], q);
            }
        }
    }
}

// ---------------------------------------------------------------------------
// gates: gates[b][d*4+e] = softmax_e(emb[b] . Wg[d][:,e] + bg[d][e])
// ---------------------------------------------------------------------------
__global__ __launch_bounds__(256)
void gates_kernel(const float* __restrict__ emb, const float* __restrict__ Wg,
                  const float* __restrict__ bg, float* __restrict__ gates)
{
    __shared__ float embS[64][116];
    __shared__ float WgS[8 * 113 * 4];
    __shared__ float bgS[32];
    const int tid = threadIdx.x;
    const int r0 = blockIdx.x << 6;

    for (int idx = tid; idx < 64 * 113; idx += 256) {
        int rr = idx / 113, kk = idx - rr * 113;
        embS[rr][kk] = emb[(long)(r0 + rr) * 113 + kk];
    }
    for (int idx = tid; idx < 8 * 113 * 4; idx += 256) WgS[idx] = Wg[idx];
    if (tid < 32) bgS[tid] = bg[tid];
    __syncthreads();

    const int q = tid & 3;
    const int r = tid >> 2;
#pragma unroll
    for (int p = 0; p < 2; ++p) {
        int d = q + p * 4;
        float lg[4] = {bgS[d * 4 + 0], bgS[d * 4 + 1], bgS[d * 4 + 2], bgS[d * 4 + 3]};
        for (int k = 0; k < 113; ++k) {
            float x = embS[r][k];
            const float* wp = &WgS[(d * 113 + k) * 4];
#pragma unroll
            for (int e = 0; e < 4; ++e) lg[e] = fmaf(x, wp[e], lg[e]);
        }
        float m = fmaxf(fmaxf(lg[0], lg[1]), fmaxf(lg[2], lg[3]));
        float ex[4], s = 0.f;
#pragma unroll
        for (int e = 0; e < 4; ++e) { ex[e] = expf(lg[e] - m); s += ex[e]; }
        float inv = 1.f / s;
        *(float4*)&gates[(long)(r0 + r) * 32 + d * 4] =
            make_float4(ex[0] * inv, ex[1] * inv, ex[2] * inv, ex[3] * inv);
    }
}

// ---------------------------------------------------------------------------
// final (per domain d): rows with dom[b]==d:
//   out[b] = sigmoid( relu(bn4(Y4d[b][:])) . w3 + b3 )
// ---------------------------------------------------------------------------
__global__ __launch_bounds__(256)
void final_kernel(const bf_t* __restrict__ Y4d, const int* __restrict__ dom,
                  const float* __restrict__ s4sum, const float* __restrict__ s4sq,
                  const float* __restrict__ g4, const float* __restrict__ b4,
                  const float* __restrict__ w3, const float* __restrict__ b3,
                  int d, float* __restrict__ out)
{
    __shared__ float sc[128], sh[128], wS[128];
    const int tid = threadIdx.x;
    if (tid < 128) {
        float m = s4sum[tid] * (1.f / B_ROWS);
        float v = s4sq[tid] * (1.f / B_ROWS) - m * m;
        float s = g4[tid] * rsqrtf(v + EPS_BN);
        sc[tid] = s;
        sh[tid] = b4[tid] - m * s;
        wS[tid] = w3[tid];
    }
    __syncthreads();
    const float bb = b3[0];
    for (long b = (long)blockIdx.x * 256 + tid; b < B_ROWS; b += (long)gridDim.x * 256) {
        if ((dom[b] & 7) == d) {
            const bf_t* yp = Y4d + b * 128;
            float acc = bb;
            for (int c = 0; c < 128; c += 8) {
                uint4 raw = *(const uint4*)(yp + c);
                u32 w4[4] = {raw.x, raw.y, raw.z, raw.w};
#pragma unroll
                for (int j = 0; j < 8; ++j) {
                    float f = bf2f((bf_t)((w4[j >> 1] >> ((j & 1) * 16)) & 0xffffu));
                    float h = fmaxf(f * sc[c + j] + sh[c + j], 0.f);
                    acc = fmaf(h, wS[c + j], acc);
                }
            }
            out[b] = 1.f / (1.f + expf(-acc));
        }
    }
}

// ---------------------------------------------------------------------------
extern "C" void kernel_launch(void* const* d_in, const int* in_sizes, int n_in,
                              void* d_out, int out_size, void* d_ws, size_t ws_size,
                              hipStream_t stream)
{
    const float* emb = (const float*)d_in[0];
    const int*   dom = (const int*)d_in[1];
    const float* We1 = (const float*)d_in[2];
    const float* be1 = (const float*)d_in[3];
    const float* eg1 = (const float*)d_in[4];
    const float* eb1 = (const float*)d_in[5];
    const float* We2 = (const float*)d_in[6];
    const float* be2 = (const float*)d_in[7];
    const float* eg2 = (const float*)d_in[8];
    const float* eb2 = (const float*)d_in[9];
    const float* Wg  = (const float*)d_in[10];
    const float* bg  = (const float*)d_in[11];
    const float* Wt1 = (const float*)d_in[12];
    const float* bt1 = (const float*)d_in[13];
    const float* tg1 = (const float*)d_in[14];
    const float* tb1 = (const float*)d_in[15];
    const float* Wt2 = (const float*)d_in[16];
    const float* bt2 = (const float*)d_in[17];
    const float* tg2 = (const float*)d_in[18];
    const float* tb2 = (const float*)d_in[19];
    const float* Wt3 = (const float*)d_in[20];
    const float* bt3 = (const float*)d_in[21];
    float* out = (float*)d_out;

    char* ws = (char*)d_ws;
    // workspace layout (peak ~244.9 MB):
    bf_t*  Y2    = (bf_t*)(ws);                    // [B][480] bf16, 125.8 MB
    float* gates = (float*)(ws + 125829120LL);     // [B][32] f32, 16.8 MB
    bf_t*  Yx    = (bf_t*)(ws + 142606336LL);      // Y1e / Y3d slot: [B][256] bf16, 67.1 MB
    bf_t*  Y4    = (bf_t*)(ws + 209715200LL);      // [B][128] bf16 (embB first), 33.55 MB
    float* S     = (float*)(ws + 243269632LL);     // raw stats, 9096 f32
    bf_t*  WTa   = (bf_t*)(ws + 243306496LL);      // transposed bf16 weights, 1.5 MB

    bf_t* embB = Y4;                 // dead before gemm5 writes Y4
    bf_t* We1T = WTa;                // [4][256][128]
    bf_t* We2T = We1T + 131072;      // [4][128][256]
    bf_t* Wt1T = We2T + 131072;      // [8][256][128]
    bf_t* Wt2T = Wt1T + 262144;      // [8][128][256]

    float* S1s = S;           float* S1q = S1s + 1024;   // [4][256]
    float* S2s = S1q + 1024;  float* S2q = S2s + 452;    // [4][113]
    float* S3s = S2q + 452;   float* S3q = S3s + 2048;   // [8][256]
    float* S4s = S3q + 2048;  float* S4q = S4s + 1024;   // [8][128]

    hipMemsetAsync(S, 0, 9096 * sizeof(float), stream);

    // ---- prep ----
    prep_w<<<512, 256, 0, stream>>>(We1, We1T, 4, 113, 256, 256, 128);
    prep_w<<<512, 256, 0, stream>>>(We2, We2T, 4, 256, 113, 128, 256);
    prep_w<<<1024, 256, 0, stream>>>(Wt1, Wt1T, 8, 113, 256, 256, 128);
    prep_w<<<1024, 256, 0, stream>>>(Wt2, Wt2T, 8, 256, 128, 128, 256);
    prep_emb<<<2048, 256, 0, stream>>>(emb, embB);

    // ---- gates ----
    gates_kernel<<<2048, 256, 0, stream>>>(emb, Wg, bg, gates);

    // ---- expert phase ----
    for (int e = 0; e < 4; ++e) {
        // gemm1: embB [B,128](113) -> Y1e [B,256] + S1[e]
        gemm_big<0, 256, 128, false><<<256, 512, 0, stream>>>(
            embB, 128, 128,
            nullptr, nullptr, nullptr, nullptr, nullptr, 0,
            We1T + (long)e * 32768,
            be1 + e * 256, 256,
            Yx, 256, 0, nullptr, 0, S1s + e * 256, S1q + e * 256);
        // gemm2: relu(bn1(Y1e)) [B,256] -> Y2[:, e*120..+113] + S2[e]
        gemm_big<1, 128, 256, false><<<256, 512, 0, stream>>>(
            Yx, 256, 256,
            nullptr, S1s + e * 256, S1q + e * 256, eg1 + e * 256, eb1 + e * 256, 256,
            We2T + (long)e * 32768,
            be2 + e * 113, 113,
            Y2, 480, e * 120, nullptr, 0, S2s + e * 113, S2q + e * 113);
    }

    // ---- tower phase ----
    for (int d = 0; d < 8; ++d) {
        // gemm4: gated mix of bn2+relu(Y2) [B,113] -> Y3d [B,256] + S3[d]
        gemm_big<2, 256, 128, false><<<256, 512, 0, stream>>>(
            Y2, 480, 113,
            gates + d * 4, S2s, S2q, eg2, eb2, 452,
            Wt1T + (long)d * 32768,
            bt1 + d * 256, 256,
            Yx, 256, 0, nullptr, 0, S3s + d * 256, S3q + d * 256);
        // gemm5: relu(bn3(Y3d)) [B,256] -> Y4d [B,128] (rows with dom==d only) + S4[d]
        gemm_big<1, 128, 256, true><<<256, 512, 0, stream>>>(
            Yx, 256, 256,
            nullptr, S3s + d * 256, S3q + d * 256, tg1 + d * 256, tb1 + d * 256, 256,
            Wt2T + (long)d * 32768,
            bt2 + d * 128, 128,
            Y4, 128, 0, dom, d, S4s + d * 128, S4q + d * 128);
        // final: select rows with dom==d, bn4+relu, dot Wt3, sigmoid
        final_kernel<<<1024, 256, 0, stream>>>(
            Y4, dom, S4s + d * 128, S4q + d * 128,
            tg2 + d * 128, tb2 + d * 128, Wt3 + d * 128, bt3 + d, d, out);
    }

    (void)in_sizes; (void)n_in; (void)out_size; (void)ws_size;
}